// Round 17
// baseline (124.775 us; speedup 1.0000x reference)
//
#include <hip/hip_runtime.h>
#include <hip/hip_bf16.h>

typedef unsigned short u16;
typedef unsigned int u32;
typedef __attribute__((ext_vector_type(4))) float f32x4;
typedef __attribute__((ext_vector_type(8))) short s16x8;
typedef __attribute__((ext_vector_type(8))) unsigned short u16x8;
typedef __attribute__((ext_vector_type(4))) unsigned short u16x4;

#define EPS_V (1e-10f)
#define TILES 4
#define NHALF (TILES * 4)       // 16 halves of 16 rows = 256 rows per block

__device__ __forceinline__ u16 f2bf(float f) {   // RNE
  unsigned u = __float_as_uint(f);
  u += 0x7fffu + ((u >> 16) & 1u);
  return (u16)(u >> 16);
}
__device__ __forceinline__ float bf2f(u16 h) {
  return __uint_as_float(((unsigned)h) << 16);
}
__device__ __forceinline__ float wred_sum(float v) {
#pragma unroll
  for (int o = 32; o; o >>= 1) v += __shfl_xor(v, o);
  return v;
}
__device__ __forceinline__ float red16(float v) {   // sum within 16-lane group
  v += __shfl_xor(v, 1); v += __shfl_xor(v, 2);
  v += __shfl_xor(v, 4); v += __shfl_xor(v, 8);
  return v;
}
__device__ __forceinline__ bool mask_at(const void* m, int kind, int idx) {
  if (kind == 0) return ((const int*)m)[idx] != 0;
  if (kind == 1) return ((const float*)m)[idx] != 0.0f;
  return ((const unsigned char*)m)[idx] != 0;
}

// ---------- K0: b0=scan, b1=mask-detect, b2..81=pack(x4), rest=zero accumulators ----------
__global__ __launch_bounds__(256) void k0_fused(
    const int* __restrict__ n_nodes, const unsigned int* __restrict__ mask_raw,
    const float* __restrict__ w_node, const float* __restrict__ W_agn,
    const float* __restrict__ W_nga, const float* __restrict__ W_qna,
    const float* __restrict__ W_qan,
    int* __restrict__ seg_start, int* __restrict__ mkind,
    float* __restrict__ zero_base, int nzero, u16* __restrict__ Wpack,
    int G, int ndw) {
  const int b = blockIdx.x;
  const int t = threadIdx.x;
  if (b == 0) {
    if (t < 64) {
      int base = t * 4;
      int v0 = (base + 0 < G) ? n_nodes[base + 0] : 0;
      int v1 = (base + 1 < G) ? n_nodes[base + 1] : 0;
      int v2 = (base + 2 < G) ? n_nodes[base + 2] : 0;
      int v3 = (base + 3 < G) ? n_nodes[base + 3] : 0;
      int lsum = v0 + v1 + v2 + v3;
      int x = lsum;
#pragma unroll
      for (int o = 1; o < 64; o <<= 1) {
        int y = __shfl_up(x, o);
        if (t >= o) x += y;
      }
      int run = x - lsum;
      if (base + 0 < G) seg_start[base + 0] = run; run += v0;
      if (base + 1 < G) seg_start[base + 1] = run; run += v1;
      if (base + 2 < G) seg_start[base + 2] = run; run += v2;
      if (base + 3 < G) seg_start[base + 3] = run; run += v3;
      if (t == 63) seg_start[G] = run;
    }
  } else if (b == 1) {
    __shared__ int notInt, notFloat;
    if (t == 0) { notInt = 0; notFloat = 0; }
    __syncthreads();
    int li = 0, lf = 0;
    for (int i = t; i < ndw; i += 256) {
      unsigned v = mask_raw[i];
      if (v != 0u && v != 1u) li = 1;
      if (v != 0u && v != 0x3F800000u) lf = 1;
    }
    if (li) atomicOr(&notInt, 1);
    if (lf) atomicOr(&notFloat, 1);
    __syncthreads();
    if (t == 0) mkind[0] = (!notInt) ? 0 : ((!notFloat) ? 1 : 2);
  } else if (b < 2 + 80) {
    int q = (b - 2) * 256 + t;        // < 20480 quads (320 cols x 64 quads)
    int col = q >> 6, k = (q & 63) * 4;
    f32x4 v = (f32x4){0.f, 0.f, 0.f, 0.f};
    if (col < 64) v = *reinterpret_cast<const f32x4*>(W_agn + col * 256 + k);
    else if (col < 128) v = *reinterpret_cast<const f32x4*>(W_nga + (col - 64) * 256 + k);
    else if (col < 192) v = *reinterpret_cast<const f32x4*>(W_qna + (col - 128) * 256 + k);
    else if (col < 256) v = *reinterpret_cast<const f32x4*>(W_qan + (col - 192) * 256 + k);
    else if (col == 256) v = *reinterpret_cast<const f32x4*>(w_node + k);
    u16x4 h;
    h[0] = f2bf(v[0]); h[1] = f2bf(v[1]); h[2] = f2bf(v[2]); h[3] = f2bf(v[3]);
    *reinterpret_cast<u16x4*>(Wpack + (size_t)q * 4) = h;
  } else {
    int idx = (b - 82) * 256 + t;
    if (idx < nzero) zero_base[idx] = 0.f;
  }
}

// fragment: 8 bf16 of LDS-row m (f32 data), k=k0..k0+7, 16B-granule XOR-(m&7)
__device__ __forceinline__ s16x8 frag_from_lds(const float* Vf, int m, int k0) {
  int g0 = ((k0 >> 2) ^ (m & 7));
  int g1 = g0 ^ 1;
  const f32x4 lo = *reinterpret_cast<const f32x4*>(&Vf[m * 256 + g0 * 4]);
  const f32x4 hi = *reinterpret_cast<const f32x4*>(&Vf[m * 256 + g1 * 4]);
  union { s16x8 v; u32 u[4]; } r;
  r.u[0] = __builtin_amdgcn_perm(__float_as_uint(lo[1]), __float_as_uint(lo[0]), 0x07060302u);
  r.u[1] = __builtin_amdgcn_perm(__float_as_uint(lo[3]), __float_as_uint(lo[2]), 0x07060302u);
  r.u[2] = __builtin_amdgcn_perm(__float_as_uint(hi[1]), __float_as_uint(hi[0]), 0x07060302u);
  r.u[3] = __builtin_amdgcn_perm(__float_as_uint(hi[3]), __float_as_uint(hi[2]), 0x07060302u);
  return r.v;
}

// ---------- K1: R16 pipeline + full segment-stat fusion.
// wave0 (agn+nl): in-reg masked row-softmax -> pa_un/Sn_at atomics (no stores).
// wave1 (nga): bf16 store + e=exp(y) -> e_lds[2] + S/V run-length atomics.
// wave2 (qna): NO store; deferred I = sum e(h-1)*qna(h-1) via e_lds + pacc.
// wave3 (qan): q_a run-length atomics. All atomics boundary-only [R9-proven].
__global__ __launch_bounds__(256, 2) void k1_gemm(
    const float* __restrict__ values, const u16* __restrict__ Wpack,
    const int* __restrict__ indices, const void* __restrict__ mask,
    const int* __restrict__ mkind,
    const float* __restrict__ b_agn, const float* __restrict__ b_nga,
    const float* __restrict__ b_qna, const float* __restrict__ b_qan,
    u16* __restrict__ nga_bf, float* __restrict__ nga_f32,
    float* __restrict__ q_a, float* __restrict__ pa_un,
    float* __restrict__ Sn_at, float* __restrict__ S_at,
    float* __restrict__ V_at, float* __restrict__ I_at, int nga_is_bf) {
  __shared__ float ring[4][16 * 256];   // 64 KB
  __shared__ u16 outbuf[16][68];        // nga staging (conflict-free)
  __shared__ float e_lds[2][16][68];    // e = exp(nga), double-buffered
  __shared__ int segid[TILES * 64];

  const int t = threadIdx.x;
  const int lane = t & 63;
  const int wave = t >> 6;              // 0 agn(+nl), 1 nga, 2 qna, 3 qan
  const int ln15 = lane & 15;
  const int kg = lane >> 4;
  const int blk0 = blockIdx.x * (TILES * 64);
  const int kind = mkind[0];

  // B fragments for this wave's 64-col chunk (L2-hot), once per block
  s16x8 bfr[4][8];
  {
    const u16* wb = Wpack + (size_t)(wave * 64 + ln15) * 256 + kg * 8;
#pragma unroll
    for (int cg = 0; cg < 4; ++cg)
#pragma unroll
      for (int s = 0; s < 8; ++s)
        bfr[cg][s] = *reinterpret_cast<const s16x8*>(wb + (size_t)(cg * 16) * 256 + s * 32);
  }
  float bias_c[4];
  {
    const float* bp = (wave == 0) ? b_agn : (wave == 1) ? b_nga
                    : (wave == 2) ? b_qna : b_qan;
#pragma unroll
    for (int cg = 0; cg < 4; ++cg) bias_c[cg] = bp[cg * 16 + ln15];
  }
  s16x8 bn[8];
  if (wave == 0) {
    const u16* wb = Wpack + (size_t)(256 + ln15) * 256 + kg * 8;
#pragma unroll
    for (int s = 0; s < 8; ++s)
      bn[s] = *reinterpret_cast<const s16x8*>(wb + s * 32);
  }
  if (wave == 3) {
#pragma unroll
    for (int j = 0; j < 4; ++j)
      segid[lane + 64 * j] = indices[blk0 + lane + 64 * j];
  }
  // run-length state per wave
  float qpart[4] = {0.f, 0.f, 0.f, 0.f};           // wave3: qan
  int qg = (wave == 3) ? segid[kg * 4] : 0;
  float pa_[4] = {0.f, 0.f, 0.f, 0.f};             // wave0: pa
  float sn_ = 0.f;
  int pg = 0;
  bool mv[4] = {false, false, false, false};
  float Ss_[4] = {0.f, 0.f, 0.f, 0.f};             // wave1: S,V
  float Vv_[4] = {0.f, 0.f, 0.f, 0.f};
  int sg = 0;
  float Ii_[4] = {0.f, 0.f, 0.f, 0.f};             // wave2: I (deferred)
  int ig = 0;
  f32x4 pacc[4];
#pragma unroll
  for (int cg = 0; cg < 4; ++cg) pacc[cg] = (f32x4){0.f, 0.f, 0.f, 0.f};
  if (wave == 0) {
    pg = indices[blk0 + kg * 4];
#pragma unroll
    for (int cg = 0; cg < 4; ++cg)
      mv[cg] = mask_at(mask, kind, pg * 64 + cg * 16 + ln15);
  } else if (wave == 1) {
    sg = indices[blk0 + kg * 4];
  } else if (wave == 2) {
    ig = indices[blk0 + kg * 4];
  }

#define STAGE(hh)                                                              \
  {                                                                            \
    float* dst_ = ring[(hh) & 3];                                              \
    const int r0_ = blk0 + (hh) * 16;                                          \
    _Pragma("unroll")                                                          \
    for (int i_ = 0; i_ < 4; ++i_) {                                           \
      int m_ = wave * 4 + i_;                                                  \
      const float* gp_ = values + (size_t)(r0_ + m_) * 256 + ((lane ^ (m_ & 7)) << 2); \
      __builtin_amdgcn_global_load_lds(                                        \
          (const __attribute__((address_space(1))) void*)gp_,                  \
          (__attribute__((address_space(3))) void*)&dst_[m_ * 256], 16, 0, 0); \
    }                                                                          \
  }

  STAGE(0);
  STAGE(1);

  for (int h = 0; h < NHALF; ++h) {
    if (h + 2 < NHALF) STAGE(h + 2);
    // counted waits. wave1: +lgkmcnt(0) so its e_lds writes are pre-barrier
    // visible to wave2. h==0: all waves fence segid (lgkmcnt(0)).
    if (h == 0) {
      asm volatile("s_waitcnt vmcnt(8) lgkmcnt(0)" ::: "memory");
    } else if (!nga_is_bf && wave == 1) {
      asm volatile("s_waitcnt vmcnt(0) lgkmcnt(0)" ::: "memory");
    } else if (h == NHALF - 1) {
      asm volatile("s_waitcnt vmcnt(0) lgkmcnt(0)" ::: "memory");
    } else if (h == NHALF - 2) {
      if (wave == 1) asm volatile("s_waitcnt vmcnt(8) lgkmcnt(0)" ::: "memory");
      else           asm volatile("s_waitcnt vmcnt(4)" ::: "memory");
    } else {
      if (wave == 1) asm volatile("s_waitcnt vmcnt(12) lgkmcnt(0)" ::: "memory");
      else           asm volatile("s_waitcnt vmcnt(8)" ::: "memory");
    }
    __builtin_amdgcn_sched_barrier(0);
    __builtin_amdgcn_s_barrier();
    __builtin_amdgcn_sched_barrier(0);

    const float* buf = ring[h & 3];
    const int row0 = blk0 + h * 16;

    f32x4 acc[4];
#pragma unroll
    for (int cg = 0; cg < 4; ++cg) acc[cg] = (f32x4){0.f, 0.f, 0.f, 0.f};
    f32x4 an0 = (f32x4){0.f, 0.f, 0.f, 0.f};

#pragma unroll
    for (int s = 0; s < 8; ++s) {
      const int k0 = s * 32 + kg * 8;
      s16x8 a0 = frag_from_lds(buf, ln15, k0);
#pragma unroll
      for (int cg = 0; cg < 4; ++cg)
        acc[cg] = __builtin_amdgcn_mfma_f32_16x16x32_bf16(a0, bfr[cg][s], acc[cg], 0, 0, 0);
      if (wave == 0)
        an0 = __builtin_amdgcn_mfma_f32_16x16x32_bf16(a0, bn[s], an0, 0, 0, 0);
    }

    // epilogue: C/D map col = lane&15, row = (lane>>4)*4 + reg  [m89/m91]
    if (wave == 0) {
      // in-register masked row-softmax -> pa_un / Sn_at run-length accumulators
#pragma unroll
      for (int r = 0; r < 4; ++r) {
        int m = kg * 4 + r;
        int g = segid[h * 16 + m];
        if (g != pg) {
#pragma unroll
          for (int cg = 0; cg < 4; ++cg) {
            atomicAdd(&pa_un[pg * 64 + cg * 16 + ln15], pa_[cg]);
            pa_[cg] = 0.f;
          }
          if (ln15 == 0) atomicAdd(&Sn_at[pg], sn_);
          sn_ = 0.f;
          pg = g;
#pragma unroll
          for (int cg = 0; cg < 4; ++cg)
            mv[cg] = mask_at(mask, kind, pg * 64 + cg * 16 + ln15);
        }
        float e0[4];
        float rs = 0.f;
#pragma unroll
        for (int cg = 0; cg < 4; ++cg) {
          e0[cg] = mv[cg] ? __expf(acc[cg][r] + bias_c[cg]) : 0.f;
          rs += e0[cg];
        }
        rs = red16(rs);
        float pn_e = __shfl(__expf(an0[r]), kg * 16);   // nl in col 0 of group
        if (ln15 == 0) sn_ += pn_e;
        if (rs > 0.f) {
          float inv = pn_e / rs;
#pragma unroll
          for (int cg = 0; cg < 4; ++cg) pa_[cg] += e0[cg] * inv;
        } else {
#pragma unroll
          for (int cg = 0; cg < 4; ++cg) pa_[cg] += pn_e * 0.015625f;
        }
      }
    } else if (wave == 1) {
      // nga: store + e -> e_lds + S/V run-length accumulators
#pragma unroll
      for (int r = 0; r < 4; ++r) {
        int m = kg * 4 + r;
        int g = segid[h * 16 + m];
        if (g != sg) {
#pragma unroll
          for (int cg = 0; cg < 4; ++cg) {
            atomicAdd(&S_at[sg * 64 + cg * 16 + ln15], Ss_[cg]);
            atomicAdd(&V_at[sg * 64 + cg * 16 + ln15], Vv_[cg]);
            Ss_[cg] = 0.f; Vv_[cg] = 0.f;
          }
          sg = g;
        }
#pragma unroll
        for (int cg = 0; cg < 4; ++cg) {
          float y = acc[cg][r] + bias_c[cg];
          float e = __expf(y);
          e_lds[h & 1][m][cg * 16 + ln15] = e;
          Ss_[cg] += e;
          Vv_[cg] += e * y;
          if (nga_is_bf) outbuf[m][cg * 16 + ln15] = f2bf(y);
          else nga_f32[(size_t)(row0 + m) * 64 + cg * 16 + ln15] = y;
        }
      }
      if (nga_is_bf) {
#pragma unroll
        for (int j = 0; j < 4; ++j) {
          int li = lane + j * 64;
          int rr = li >> 4, cc = (li & 15) * 4;
          u16x4 v = *reinterpret_cast<const u16x4*>(&outbuf[rr][cc]);
          *reinterpret_cast<u16x4*>(nga_bf + (size_t)row0 * 64 + (size_t)li * 4) = v;
        }
      }
    } else if (wave == 2) {
      // deferred I: consume e(h-1) against pacc (qna of half h-1)
      if (h > 0) {
        const int hp = h - 1;
#pragma unroll
        for (int r = 0; r < 4; ++r) {
          int m = kg * 4 + r;
          int g = segid[hp * 16 + m];
          if (g != ig) {
#pragma unroll
            for (int cg = 0; cg < 4; ++cg) {
              atomicAdd(&I_at[ig * 64 + cg * 16 + ln15], Ii_[cg]);
              Ii_[cg] = 0.f;
            }
            ig = g;
          }
#pragma unroll
          for (int cg = 0; cg < 4; ++cg)
            Ii_[cg] += e_lds[hp & 1][m][cg * 16 + ln15] * (pacc[cg][r] + bias_c[cg]);
        }
      }
#pragma unroll
      for (int cg = 0; cg < 4; ++cg) pacc[cg] = acc[cg];
    } else {
      // wave3 qan: run-length accumulate; atomics only at segment boundaries
#pragma unroll
      for (int r = 0; r < 4; ++r) {
        int m = kg * 4 + r;
        int g = segid[h * 16 + m];
        if (g != qg) {
#pragma unroll
          for (int cg = 0; cg < 4; ++cg) {
            atomicAdd(&q_a[qg * 64 + cg * 16 + ln15], qpart[cg]);
            qpart[cg] = 0.f;
          }
          qg = g;
        }
#pragma unroll
        for (int cg = 0; cg < 4; ++cg)
          qpart[cg] += acc[cg][r] + bias_c[cg];
      }
    }
  }
#undef STAGE

  // fence wave1's final e_lds writes, then drain wave2's last half + flushes
  asm volatile("s_waitcnt lgkmcnt(0)" ::: "memory");
  __builtin_amdgcn_sched_barrier(0);
  __builtin_amdgcn_s_barrier();
  __builtin_amdgcn_sched_barrier(0);

  if (wave == 0) {
#pragma unroll
    for (int cg = 0; cg < 4; ++cg)
      atomicAdd(&pa_un[pg * 64 + cg * 16 + ln15], pa_[cg]);
    if (ln15 == 0) atomicAdd(&Sn_at[pg], sn_);
  } else if (wave == 1) {
#pragma unroll
    for (int cg = 0; cg < 4; ++cg) {
      atomicAdd(&S_at[sg * 64 + cg * 16 + ln15], Ss_[cg]);
      atomicAdd(&V_at[sg * 64 + cg * 16 + ln15], Vv_[cg]);
    }
  } else if (wave == 2) {
    const int hp = NHALF - 1;
#pragma unroll
    for (int r = 0; r < 4; ++r) {
      int m = kg * 4 + r;
      int g = segid[hp * 16 + m];
      if (g != ig) {
#pragma unroll
        for (int cg = 0; cg < 4; ++cg) {
          atomicAdd(&I_at[ig * 64 + cg * 16 + ln15], Ii_[cg]);
          Ii_[cg] = 0.f;
        }
        ig = g;
      }
#pragma unroll
      for (int cg = 0; cg < 4; ++cg)
        Ii_[cg] += e_lds[hp & 1][m][cg * 16 + ln15] * (pacc[cg][r] + bias_c[cg]);
    }
#pragma unroll
    for (int cg = 0; cg < 4; ++cg)
      atomicAdd(&I_at[ig * 64 + cg * 16 + ln15], Ii_[cg]);
  } else {
#pragma unroll
    for (int cg = 0; cg < 4; ++cg)
      atomicAdd(&q_a[qg * 64 + cg * 16 + ln15], qpart[cg]);
  }
}

// ---------- K2: finalize from atomic stats + fused pna sweep ----------
__global__ __launch_bounds__(1024) void k2_segment(
    const u16* __restrict__ nga_bf, float* __restrict__ nga_f32,
    const int* __restrict__ seg_start, const void* __restrict__ mask,
    const int* __restrict__ mkind,
    const float* __restrict__ q_a, const float* __restrict__ pa_un,
    const float* __restrict__ Sn_at, const float* __restrict__ S_at,
    const float* __restrict__ V_at, const float* __restrict__ I_at,
    const int* __restrict__ n_nodes,
    float* __restrict__ p_a, float* __restrict__ entropy, float* __restrict__ value,
    float* __restrict__ Su, float* __restrict__ pna, int nga_is_bf) {
  const int g = blockIdx.x;
  const int s = seg_start[g], e = seg_start[g + 1];
  const int t = threadIdx.x;

  __shared__ float sS[64];

  if (t < 64) {
    int a = t;
    int n = n_nodes[g];
    float S = S_at[g * 64 + a];
    float V = V_at[g * 64 + a];
    float I = I_at[g * 64 + a];
    float Sn = Sn_at[g];
    float P = (Sn > 0.f) ? pa_un[g * 64 + a] / Sn : 0.f;
    p_a[g * 64 + a] = P;
    Su[g * 64 + a] = S;
    sS[a] = (S > 0.f) ? 1.f / S : 0.f;
    float inner = (S > 0.f) ? I / S : 0.f;
    float Q = q_a[g * 64 + a];
    bool mva = mask_at(mask, mkind[0], g * 64 + a);
    float Hn;
    if (n <= 0) Hn = 0.f;
    else if (!mva) Hn = -logf(1.0f / (float)n + EPS_V);
    else Hn = (S > 0.f) ? (logf(S) - V / S) : 0.f;
    float ent_c = -P * logf(P + EPS_V) + P * Hn;
    float val_c = P * (Q + inner);
    ent_c = wred_sum(ent_c);
    val_c = wred_sum(val_c);
    if (a == 0) { entropy[g] = ent_c; value[g] = val_c; }
  }
  __syncthreads();   // sS visible

  // pna sweep: p_n__a = exp(nga)/Su
  const int a0 = (t & 7) * 8;
  float is0 = sS[a0 + 0], is1 = sS[a0 + 1], is2 = sS[a0 + 2], is3 = sS[a0 + 3];
  float is4 = sS[a0 + 4], is5 = sS[a0 + 5], is6 = sS[a0 + 6], is7 = sS[a0 + 7];
  for (int i = s + (t >> 3); i < e; i += 128) {
    size_t base = (size_t)i * 64 + a0;
    float4 o0, o1;
    if (nga_is_bf) {
      u16x8 y = *reinterpret_cast<const u16x8*>(nga_bf + base);
      o0.x = __expf(bf2f(y[0])) * is0; o0.y = __expf(bf2f(y[1])) * is1;
      o0.z = __expf(bf2f(y[2])) * is2; o0.w = __expf(bf2f(y[3])) * is3;
      o1.x = __expf(bf2f(y[4])) * is4; o1.y = __expf(bf2f(y[5])) * is5;
      o1.z = __expf(bf2f(y[6])) * is6; o1.w = __expf(bf2f(y[7])) * is7;
    } else {
      const float4* src = reinterpret_cast<const float4*>(nga_f32 + base);
      float4 x0 = src[0], x1 = src[1];
      o0.x = __expf(x0.x) * is0; o0.y = __expf(x0.y) * is1;
      o0.z = __expf(x0.z) * is2; o0.w = __expf(x0.w) * is3;
      o1.x = __expf(x1.x) * is4; o1.y = __expf(x1.y) * is5;
      o1.z = __expf(x1.z) * is6; o1.w = __expf(x1.w) * is7;
    }
    float4* dst = reinterpret_cast<float4*>(pna + base);
    dst[0] = o0; dst[1] = o1;
  }
}

// ---------- K3: logprob ----------
__global__ __launch_bounds__(256) void k3_logprob(
    const float* __restrict__ p_a, const u16* __restrict__ nga_bf,
    const float* __restrict__ nga_f32, const int* __restrict__ indices,
    const int* __restrict__ a_action, const int* __restrict__ a_node,
    const void* __restrict__ mask, const int* __restrict__ mkind,
    const int* __restrict__ n_nodes, const float* __restrict__ Su,
    float* __restrict__ logprob, int G, int nga_is_bf) {
  int g = blockIdx.x * blockDim.x + threadIdx.x;
  if (g >= G) return;
  int kind = mkind[0];
  int a = a_action[g];
  float t1 = logf(p_a[g * 64 + a] + EPS_V);
  int node = a_node[g];
  int g2 = indices[node];
  float p2;
  if (mask_at(mask, kind, g2 * 64 + a)) {
    float S = Su[g2 * 64 + a];
    float y = nga_is_bf ? bf2f(nga_bf[(size_t)node * 64 + a]) : nga_f32[(size_t)node * 64 + a];
    p2 = (S > 0.f) ? __expf(y) / S : 0.f;
  } else {
    p2 = 1.0f / (float)n_nodes[g2];
  }
  logprob[g] = t1 + logf(p2 + EPS_V);
}

extern "C" void kernel_launch(void* const* d_in, const int* in_sizes, int n_in,
                              void* d_out, int out_size, void* d_ws, size_t ws_size,
                              hipStream_t stream) {
  const float* values = (const float*)d_in[0];
  const int* indices = (const int*)d_in[1];
  const int* a_action = (const int*)d_in[2];
  const int* a_node = (const int*)d_in[3];
  const void* action_mask = d_in[4];
  const int* n_nodes = (const int*)d_in[5];
  const float* w_node = (const float*)d_in[6];
  const float* W_agn = (const float*)d_in[7];
  const float* b_agn = (const float*)d_in[8];
  const float* W_nga = (const float*)d_in[9];
  const float* b_nga = (const float*)d_in[10];
  const float* W_qna = (const float*)d_in[11];
  const float* b_qna = (const float*)d_in[12];
  const float* W_qan = (const float*)d_in[13];
  const float* b_qan = (const float*)d_in[14];

  const int N = in_sizes[1];   // 131072
  const int G = in_sizes[2];   // 256
  const int GA = in_sizes[4];  // G*64

  float* out = (float*)d_out;
  float* o_logprob = out;
  float* o_entropy = out + G;
  float* o_value = out + 2 * G;
  float* o_pa = out + 3 * G;
  float* o_pna = out + 3 * G + GA;

  char* w = (char*)d_ws;
  size_t off = 0;
  float* Su = (float*)(w + off); off += (size_t)GA * 4;
  float* zero_base = (float*)(w + off);
  float* q_a = (float*)(w + off); off += (size_t)GA * 4;
  float* pa_un = (float*)(w + off); off += (size_t)GA * 4;
  float* S_at = (float*)(w + off); off += (size_t)GA * 4;
  float* V_at = (float*)(w + off); off += (size_t)GA * 4;
  float* I_at = (float*)(w + off); off += (size_t)GA * 4;
  float* Sn_at = (float*)(w + off); off += (size_t)G * 4;
  int nzero = 5 * GA + G;
  int* seg_start = (int*)(w + off); off += (size_t)(G + 1) * 4;
  int* mkind = (int*)(w + off); off += 256;
  off = (off + 255) & ~(size_t)255;
  u16* Wpack = (u16*)(w + off); off += (size_t)320 * 256 * 2;
  u16* nga_bf = (u16*)(w + off);
  size_t need_bf = off + (size_t)N * 64 * 2;
  int nga_is_bf = (ws_size >= need_bf) ? 1 : 0;
  float* nga_f32 = o_pna;   // fallback: f32 logits staged in d_out, sweep in-place

  int zero_blocks = (nzero + 255) / 256;
  k0_fused<<<2 + 80 + zero_blocks, 256, 0, stream>>>(
      n_nodes, (const unsigned int*)action_mask, w_node, W_agn, W_nga, W_qna, W_qan,
      seg_start, mkind, zero_base, nzero, Wpack, G, GA / 4);
  k1_gemm<<<N / (TILES * 64), 256, 0, stream>>>(
      values, Wpack, indices, action_mask, mkind,
      b_agn, b_nga, b_qna, b_qan,
      nga_bf, nga_f32, q_a, pa_un, Sn_at, S_at, V_at, I_at, nga_is_bf);
  k2_segment<<<G, 1024, 0, stream>>>(nga_bf, nga_f32, seg_start,
                                     action_mask, mkind, q_a, pa_un, Sn_at,
                                     S_at, V_at, I_at, n_nodes,
                                     o_pa, o_entropy, o_value, Su, o_pna, nga_is_bf);
  k3_logprob<<<(G + 255) / 256, 256, 0, stream>>>(
      o_pa, nga_bf, nga_f32, indices, a_action, a_node,
      action_mask, mkind, n_nodes, Su, o_logprob, G, nga_is_bf);
}

// Round 18
// 95.321 us; speedup vs baseline: 1.3090x; 1.3090x over previous
//
#include <hip/hip_runtime.h>
#include <hip/hip_bf16.h>

typedef unsigned short u16;
typedef unsigned int u32;
typedef __attribute__((ext_vector_type(4))) float f32x4;
typedef __attribute__((ext_vector_type(8))) short s16x8;
typedef __attribute__((ext_vector_type(8))) unsigned short u16x8;
typedef __attribute__((ext_vector_type(4))) unsigned short u16x4;

#define EPS_V (1e-10f)
#define TILES 4
#define NHALF (TILES * 4)       // 16 halves of 16 rows = 256 rows per block

__device__ __forceinline__ u16 f2bf(float f) {   // RNE
  unsigned u = __float_as_uint(f);
  u += 0x7fffu + ((u >> 16) & 1u);
  return (u16)(u >> 16);
}
__device__ __forceinline__ float bf2f(u16 h) {
  return __uint_as_float(((unsigned)h) << 16);
}
__device__ __forceinline__ float wred_sum(float v) {
#pragma unroll
  for (int o = 32; o; o >>= 1) v += __shfl_xor(v, o);
  return v;
}
__device__ __forceinline__ float red16(float v) {   // sum within 16-lane group
  v += __shfl_xor(v, 1); v += __shfl_xor(v, 2);
  v += __shfl_xor(v, 4); v += __shfl_xor(v, 8);
  return v;
}
__device__ __forceinline__ bool mask_at(const void* m, int kind, int idx) {
  if (kind == 0) return ((const int*)m)[idx] != 0;
  if (kind == 1) return ((const float*)m)[idx] != 0.0f;
  return ((const unsigned char*)m)[idx] != 0;
}

// ---------- K0: b0=scan, b1=mask-detect, b2..81=pack(x4), rest=zero accumulators ----------
__global__ __launch_bounds__(256) void k0_fused(
    const int* __restrict__ n_nodes, const unsigned int* __restrict__ mask_raw,
    const float* __restrict__ w_node, const float* __restrict__ W_agn,
    const float* __restrict__ W_nga, const float* __restrict__ W_qna,
    const float* __restrict__ W_qan,
    int* __restrict__ seg_start, int* __restrict__ mkind,
    float* __restrict__ zero_base, int nzero, u16* __restrict__ Wpack,
    int G, int ndw) {
  const int b = blockIdx.x;
  const int t = threadIdx.x;
  if (b == 0) {
    if (t < 64) {
      int base = t * 4;
      int v0 = (base + 0 < G) ? n_nodes[base + 0] : 0;
      int v1 = (base + 1 < G) ? n_nodes[base + 1] : 0;
      int v2 = (base + 2 < G) ? n_nodes[base + 2] : 0;
      int v3 = (base + 3 < G) ? n_nodes[base + 3] : 0;
      int lsum = v0 + v1 + v2 + v3;
      int x = lsum;
#pragma unroll
      for (int o = 1; o < 64; o <<= 1) {
        int y = __shfl_up(x, o);
        if (t >= o) x += y;
      }
      int run = x - lsum;
      if (base + 0 < G) seg_start[base + 0] = run; run += v0;
      if (base + 1 < G) seg_start[base + 1] = run; run += v1;
      if (base + 2 < G) seg_start[base + 2] = run; run += v2;
      if (base + 3 < G) seg_start[base + 3] = run; run += v3;
      if (t == 63) seg_start[G] = run;
    }
  } else if (b == 1) {
    __shared__ int notInt, notFloat;
    if (t == 0) { notInt = 0; notFloat = 0; }
    __syncthreads();
    int li = 0, lf = 0;
    for (int i = t; i < ndw; i += 256) {
      unsigned v = mask_raw[i];
      if (v != 0u && v != 1u) li = 1;
      if (v != 0u && v != 0x3F800000u) lf = 1;
    }
    if (li) atomicOr(&notInt, 1);
    if (lf) atomicOr(&notFloat, 1);
    __syncthreads();
    if (t == 0) mkind[0] = (!notInt) ? 0 : ((!notFloat) ? 1 : 2);
  } else if (b < 2 + 80) {
    int q = (b - 2) * 256 + t;        // < 20480 quads (320 cols x 64 quads)
    int col = q >> 6, k = (q & 63) * 4;
    f32x4 v = (f32x4){0.f, 0.f, 0.f, 0.f};
    if (col < 64) v = *reinterpret_cast<const f32x4*>(W_agn + col * 256 + k);
    else if (col < 128) v = *reinterpret_cast<const f32x4*>(W_nga + (col - 64) * 256 + k);
    else if (col < 192) v = *reinterpret_cast<const f32x4*>(W_qna + (col - 128) * 256 + k);
    else if (col < 256) v = *reinterpret_cast<const f32x4*>(W_qan + (col - 192) * 256 + k);
    else if (col == 256) v = *reinterpret_cast<const f32x4*>(w_node + k);
    u16x4 h;
    h[0] = f2bf(v[0]); h[1] = f2bf(v[1]); h[2] = f2bf(v[2]); h[3] = f2bf(v[3]);
    *reinterpret_cast<u16x4*>(Wpack + (size_t)q * 4) = h;
  } else {
    int idx = (b - 82) * 256 + t;
    if (idx < nzero) zero_base[idx] = 0.f;
  }
}

// fragment: 8 bf16 of LDS-row m (f32 data), k=k0..k0+7, 16B-granule XOR-(m&7)
__device__ __forceinline__ s16x8 frag_from_lds(const float* Vf, int m, int k0) {
  int g0 = ((k0 >> 2) ^ (m & 7));
  int g1 = g0 ^ 1;
  const f32x4 lo = *reinterpret_cast<const f32x4*>(&Vf[m * 256 + g0 * 4]);
  const f32x4 hi = *reinterpret_cast<const f32x4*>(&Vf[m * 256 + g1 * 4]);
  union { s16x8 v; u32 u[4]; } r;
  r.u[0] = __builtin_amdgcn_perm(__float_as_uint(lo[1]), __float_as_uint(lo[0]), 0x07060302u);
  r.u[1] = __builtin_amdgcn_perm(__float_as_uint(lo[3]), __float_as_uint(lo[2]), 0x07060302u);
  r.u[2] = __builtin_amdgcn_perm(__float_as_uint(hi[1]), __float_as_uint(hi[0]), 0x07060302u);
  r.u[3] = __builtin_amdgcn_perm(__float_as_uint(hi[3]), __float_as_uint(hi[2]), 0x07060302u);
  return r.v;
}

// ---------- K1: R15 pipeline + in-register pa/Sn reduction on wave 0.
// Wave 0 (agn + nl): NO global stores — masked row-softmax in registers,
// run-length atomics (pa_un, Sn_at) at segment boundaries [q_a-proven pattern].
// Waves 1/2 (nga/qna): coalesced stores via padded LDS. Wave 3 (qan): q_a atomics.
__global__ __launch_bounds__(256, 2) void k1_gemm(
    const float* __restrict__ values, const u16* __restrict__ Wpack,
    const int* __restrict__ indices, const void* __restrict__ mask,
    const int* __restrict__ mkind,
    const float* __restrict__ b_agn, const float* __restrict__ b_nga,
    const float* __restrict__ b_qna, const float* __restrict__ b_qan,
    u16* __restrict__ nga_bf, float* __restrict__ nga_f32,
    u16* __restrict__ qna, float* __restrict__ q_a,
    float* __restrict__ pa_un, float* __restrict__ Sn_at, int nga_is_bf) {
  __shared__ float ring[4][16 * 256];   // 64 KB
  __shared__ u16 outbuf[2][16][68];     // nga, qna staging (conflict-free)
  __shared__ int segid[TILES * 64];

  const int t = threadIdx.x;
  const int lane = t & 63;
  const int wave = t >> 6;              // 0 agn(+nl), 1 nga, 2 qna, 3 qan
  const int ln15 = lane & 15;
  const int kg = lane >> 4;
  const int blk0 = blockIdx.x * (TILES * 64);
  const int kind = mkind[0];

  // B fragments for this wave's 64-col chunk (L2-hot), once per block
  s16x8 bfr[4][8];
  {
    const u16* wb = Wpack + (size_t)(wave * 64 + ln15) * 256 + kg * 8;
#pragma unroll
    for (int cg = 0; cg < 4; ++cg)
#pragma unroll
      for (int s = 0; s < 8; ++s)
        bfr[cg][s] = *reinterpret_cast<const s16x8*>(wb + (size_t)(cg * 16) * 256 + s * 32);
  }
  float bias_c[4];
  {
    const float* bp = (wave == 0) ? b_agn : (wave == 1) ? b_nga
                    : (wave == 2) ? b_qna : b_qan;
#pragma unroll
    for (int cg = 0; cg < 4; ++cg) bias_c[cg] = bp[cg * 16 + ln15];
  }
  s16x8 bn[8];
  if (wave == 0) {
    const u16* wb = Wpack + (size_t)(256 + ln15) * 256 + kg * 8;
#pragma unroll
    for (int s = 0; s < 8; ++s)
      bn[s] = *reinterpret_cast<const s16x8*>(wb + s * 32);
  }
  if (wave == 3) {
#pragma unroll
    for (int j = 0; j < 4; ++j)
      segid[lane + 64 * j] = indices[blk0 + lane + 64 * j];
  }
  // run-length state: wave 3 -> q_a; wave 0 -> pa_un/Sn_at
  float qpart[4] = {0.f, 0.f, 0.f, 0.f};
  int qg = (wave == 3) ? segid[kg * 4] : 0;
  float pa_[4] = {0.f, 0.f, 0.f, 0.f};
  float sn_ = 0.f;
  int pg = 0;
  bool mv[4] = {false, false, false, false};
  if (wave == 0) {
    pg = indices[blk0 + kg * 4];
#pragma unroll
    for (int cg = 0; cg < 4; ++cg)
      mv[cg] = mask_at(mask, kind, pg * 64 + cg * 16 + ln15);
  }

#define STAGE(hh)                                                              \
  {                                                                            \
    float* dst_ = ring[(hh) & 3];                                              \
    const int r0_ = blk0 + (hh) * 16;                                          \
    _Pragma("unroll")                                                          \
    for (int i_ = 0; i_ < 4; ++i_) {                                           \
      int m_ = wave * 4 + i_;                                                  \
      const float* gp_ = values + (size_t)(r0_ + m_) * 256 + ((lane ^ (m_ & 7)) << 2); \
      __builtin_amdgcn_global_load_lds(                                        \
          (const __attribute__((address_space(1))) void*)gp_,                  \
          (__attribute__((address_space(3))) void*)&dst_[m_ * 256], 16, 0, 0); \
    }                                                                          \
  }

  STAGE(0);
  STAGE(1);

  for (int h = 0; h < NHALF; ++h) {
    if (h + 2 < NHALF) STAGE(h + 2);
    // counted waits: drain own loads(h); keep younger loads+stores in flight.
    // wave0 storeless (atomics uncounted -> waits conservatively correct).
    if (h == 0) {
      asm volatile("s_waitcnt vmcnt(8) lgkmcnt(0)" ::: "memory");  // + segid fence
    } else if (!nga_is_bf && wave == 1) {
      asm volatile("s_waitcnt vmcnt(0)" ::: "memory");
    } else if (h == NHALF - 1) {
      asm volatile("s_waitcnt vmcnt(0)" ::: "memory");
    } else if (h == NHALF - 2) {
      if (wave == 1 || wave == 2) asm volatile("s_waitcnt vmcnt(8)" ::: "memory");
      else                        asm volatile("s_waitcnt vmcnt(4)" ::: "memory");
    } else {
      if (wave == 1 || wave == 2) asm volatile("s_waitcnt vmcnt(12)" ::: "memory");
      else                        asm volatile("s_waitcnt vmcnt(8)" ::: "memory");
    }
    __builtin_amdgcn_sched_barrier(0);
    __builtin_amdgcn_s_barrier();
    __builtin_amdgcn_sched_barrier(0);

    const float* buf = ring[h & 3];
    const int row0 = blk0 + h * 16;

    f32x4 acc[4];
#pragma unroll
    for (int cg = 0; cg < 4; ++cg) acc[cg] = (f32x4){0.f, 0.f, 0.f, 0.f};
    f32x4 an0 = (f32x4){0.f, 0.f, 0.f, 0.f};

#pragma unroll
    for (int s = 0; s < 8; ++s) {
      const int k0 = s * 32 + kg * 8;
      s16x8 a0 = frag_from_lds(buf, ln15, k0);
#pragma unroll
      for (int cg = 0; cg < 4; ++cg)
        acc[cg] = __builtin_amdgcn_mfma_f32_16x16x32_bf16(a0, bfr[cg][s], acc[cg], 0, 0, 0);
      if (wave == 0)
        an0 = __builtin_amdgcn_mfma_f32_16x16x32_bf16(a0, bn[s], an0, 0, 0, 0);
    }

    // epilogue: C/D map col = lane&15, row = (lane>>4)*4 + reg  [m89/m91]
    if (wave == 0) {
      // in-register masked row-softmax -> pa_un / Sn_at run-length accumulators
#pragma unroll
      for (int r = 0; r < 4; ++r) {
        int m = kg * 4 + r;
        int g = segid[h * 16 + m];
        if (g != pg) {
#pragma unroll
          for (int cg = 0; cg < 4; ++cg) {
            atomicAdd(&pa_un[pg * 64 + cg * 16 + ln15], pa_[cg]);
            pa_[cg] = 0.f;
          }
          if (ln15 == 0) atomicAdd(&Sn_at[pg], sn_);
          sn_ = 0.f;
          pg = g;
#pragma unroll
          for (int cg = 0; cg < 4; ++cg)
            mv[cg] = mask_at(mask, kind, pg * 64 + cg * 16 + ln15);
        }
        float e0[4];
        float rs = 0.f;
#pragma unroll
        for (int cg = 0; cg < 4; ++cg) {
          e0[cg] = mv[cg] ? __expf(acc[cg][r] + bias_c[cg]) : 0.f;
          rs += e0[cg];
        }
        rs = red16(rs);
        float pn_e = __shfl(__expf(an0[r]), kg * 16);   // nl in col 0 of group
        if (ln15 == 0) sn_ += pn_e;
        if (rs > 0.f) {
          float inv = pn_e / rs;
#pragma unroll
          for (int cg = 0; cg < 4; ++cg) pa_[cg] += e0[cg] * inv;
        } else {
#pragma unroll
          for (int cg = 0; cg < 4; ++cg) pa_[cg] += pn_e * 0.015625f;
        }
      }
    } else if (wave == 3) {
      // qan: run-length accumulate; atomics only at segment boundaries
#pragma unroll
      for (int r = 0; r < 4; ++r) {
        int m = kg * 4 + r;
        int g = segid[h * 16 + m];
        if (g != qg) {
#pragma unroll
          for (int cg = 0; cg < 4; ++cg) {
            atomicAdd(&q_a[qg * 64 + cg * 16 + ln15], qpart[cg]);
            qpart[cg] = 0.f;
          }
          qg = g;
        }
#pragma unroll
        for (int cg = 0; cg < 4; ++cg)
          qpart[cg] += acc[cg][r] + bias_c[cg];
      }
    } else if (wave == 1 && !nga_is_bf) {
#pragma unroll
      for (int r = 0; r < 4; ++r)
#pragma unroll
        for (int cg = 0; cg < 4; ++cg)
          nga_f32[(size_t)(row0 + kg * 4 + r) * 64 + cg * 16 + ln15] = acc[cg][r] + bias_c[cg];
    } else {
      // waves 1/2: transpose through LDS -> 4 coalesced 512B stores
#pragma unroll
      for (int r = 0; r < 4; ++r) {
        int m = kg * 4 + r;
#pragma unroll
        for (int cg = 0; cg < 4; ++cg)
          outbuf[wave - 1][m][cg * 16 + ln15] = f2bf(acc[cg][r] + bias_c[cg]);
      }
      u16* dstp = (wave == 1) ? nga_bf : qna;
#pragma unroll
      for (int j = 0; j < 4; ++j) {
        int li = lane + j * 64;
        int rr = li >> 4, cc = (li & 15) * 4;
        u16x4 v = *reinterpret_cast<const u16x4*>(&outbuf[wave - 1][rr][cc]);
        *reinterpret_cast<u16x4*>(dstp + (size_t)row0 * 64 + (size_t)li * 4) = v;
      }
    }
  }
#undef STAGE

  if (wave == 3) {
#pragma unroll
    for (int cg = 0; cg < 4; ++cg)
      atomicAdd(&q_a[qg * 64 + cg * 16 + ln15], qpart[cg]);
  }
  if (wave == 0) {
#pragma unroll
    for (int cg = 0; cg < 4; ++cg)
      atomicAdd(&pa_un[pg * 64 + cg * 16 + ln15], pa_[cg]);
    if (ln15 == 0) atomicAdd(&Sn_at[pg], sn_);
  }
}

// ---------- K2: nga/qna segment stats (shuffle-free) + finalize + pna sweep ----------
__global__ __launch_bounds__(1024) void k2_segment(
    const u16* __restrict__ nga_bf, float* __restrict__ nga_f32,
    const u16* __restrict__ qna, const int* __restrict__ seg_start,
    const void* __restrict__ mask, const int* __restrict__ mkind,
    const float* __restrict__ q_a, const float* __restrict__ pa_un,
    const float* __restrict__ Sn_at,
    float* __restrict__ p_a, float* __restrict__ entropy, float* __restrict__ value,
    float* __restrict__ Su, float* __restrict__ pna, int nga_is_bf) {
  const int g = blockIdx.x;
  const int s = seg_start[g], e = seg_start[g + 1];
  const int n = e - s;
  const int t = threadIdx.x, lane = t & 63, wave = t >> 6;

  __shared__ float cs[16][64], cv[16][64], ci[16][64];
  __shared__ float sS[64];

  // phase B: per-lane independent nga/qna stats (no shuffles)
  float s_u = 0.f, v_u = 0.f, i_u = 0.f;
  for (int i = s + wave; i < e; i += 16) {
    size_t base = (size_t)i * 64 + lane;
    float y = nga_is_bf ? bf2f(nga_bf[base]) : nga_f32[base];
    float ey = __expf(y);
    s_u += ey;
    v_u += ey * y;
    i_u += ey * bf2f(qna[base]);
  }
  cs[wave][lane] = s_u; cv[wave][lane] = v_u; ci[wave][lane] = i_u;
  __syncthreads();

  const int kind = mkind[0];
  if (t < 64) {
    int a = t;
    float S = 0.f, V = 0.f, I = 0.f;
#pragma unroll
    for (int w = 0; w < 16; ++w) { S += cs[w][a]; V += cv[w][a]; I += ci[w][a]; }
    float Sn = Sn_at[g];
    float P = (Sn > 0.f) ? pa_un[g * 64 + a] / Sn : 0.f;
    p_a[g * 64 + a] = P;
    Su[g * 64 + a] = S;
    sS[a] = (S > 0.f) ? 1.f / S : 0.f;
    float inner = (S > 0.f) ? I / S : 0.f;
    float Q = q_a[g * 64 + a];
    bool mva = mask_at(mask, kind, g * 64 + a);
    float Hn;
    if (n <= 0) Hn = 0.f;
    else if (!mva) Hn = -logf(1.0f / (float)n + EPS_V);
    else Hn = (S > 0.f) ? (logf(S) - V / S) : 0.f;
    float ent_c = -P * logf(P + EPS_V) + P * Hn;
    float val_c = P * (Q + inner);
    ent_c = wred_sum(ent_c);
    val_c = wred_sum(val_c);
    if (a == 0) { entropy[g] = ent_c; value[g] = val_c; }
  }
  __syncthreads();   // sS visible

  // fused pna sweep: p_n__a = exp(nga)/Su
  const int a0 = (t & 7) * 8;
  float is0 = sS[a0 + 0], is1 = sS[a0 + 1], is2 = sS[a0 + 2], is3 = sS[a0 + 3];
  float is4 = sS[a0 + 4], is5 = sS[a0 + 5], is6 = sS[a0 + 6], is7 = sS[a0 + 7];
  for (int i = s + (t >> 3); i < e; i += 128) {
    size_t base = (size_t)i * 64 + a0;
    float4 o0, o1;
    if (nga_is_bf) {
      u16x8 y = *reinterpret_cast<const u16x8*>(nga_bf + base);
      o0.x = __expf(bf2f(y[0])) * is0; o0.y = __expf(bf2f(y[1])) * is1;
      o0.z = __expf(bf2f(y[2])) * is2; o0.w = __expf(bf2f(y[3])) * is3;
      o1.x = __expf(bf2f(y[4])) * is4; o1.y = __expf(bf2f(y[5])) * is5;
      o1.z = __expf(bf2f(y[6])) * is6; o1.w = __expf(bf2f(y[7])) * is7;
    } else {
      const float4* src = reinterpret_cast<const float4*>(nga_f32 + base);
      float4 x0 = src[0], x1 = src[1];
      o0.x = __expf(x0.x) * is0; o0.y = __expf(x0.y) * is1;
      o0.z = __expf(x0.z) * is2; o0.w = __expf(x0.w) * is3;
      o1.x = __expf(x1.x) * is4; o1.y = __expf(x1.y) * is5;
      o1.z = __expf(x1.z) * is6; o1.w = __expf(x1.w) * is7;
    }
    float4* dst = reinterpret_cast<float4*>(pna + base);
    dst[0] = o0; dst[1] = o1;
  }
}

// ---------- K3: logprob ----------
__global__ __launch_bounds__(256) void k3_logprob(
    const float* __restrict__ p_a, const u16* __restrict__ nga_bf,
    const float* __restrict__ nga_f32, const int* __restrict__ indices,
    const int* __restrict__ a_action, const int* __restrict__ a_node,
    const void* __restrict__ mask, const int* __restrict__ mkind,
    const int* __restrict__ n_nodes, const float* __restrict__ Su,
    float* __restrict__ logprob, int G, int nga_is_bf) {
  int g = blockIdx.x * blockDim.x + threadIdx.x;
  if (g >= G) return;
  int kind = mkind[0];
  int a = a_action[g];
  float t1 = logf(p_a[g * 64 + a] + EPS_V);
  int node = a_node[g];
  int g2 = indices[node];
  float p2;
  if (mask_at(mask, kind, g2 * 64 + a)) {
    float S = Su[g2 * 64 + a];
    float y = nga_is_bf ? bf2f(nga_bf[(size_t)node * 64 + a]) : nga_f32[(size_t)node * 64 + a];
    p2 = (S > 0.f) ? __expf(y) / S : 0.f;
  } else {
    p2 = 1.0f / (float)n_nodes[g2];
  }
  logprob[g] = t1 + logf(p2 + EPS_V);
}

extern "C" void kernel_launch(void* const* d_in, const int* in_sizes, int n_in,
                              void* d_out, int out_size, void* d_ws, size_t ws_size,
                              hipStream_t stream) {
  const float* values = (const float*)d_in[0];
  const int* indices = (const int*)d_in[1];
  const int* a_action = (const int*)d_in[2];
  const int* a_node = (const int*)d_in[3];
  const void* action_mask = d_in[4];
  const int* n_nodes = (const int*)d_in[5];
  const float* w_node = (const float*)d_in[6];
  const float* W_agn = (const float*)d_in[7];
  const float* b_agn = (const float*)d_in[8];
  const float* W_nga = (const float*)d_in[9];
  const float* b_nga = (const float*)d_in[10];
  const float* W_qna = (const float*)d_in[11];
  const float* b_qna = (const float*)d_in[12];
  const float* W_qan = (const float*)d_in[13];
  const float* b_qan = (const float*)d_in[14];

  const int N = in_sizes[1];   // 131072
  const int G = in_sizes[2];   // 256
  const int GA = in_sizes[4];  // G*64

  float* out = (float*)d_out;
  float* o_logprob = out;
  float* o_entropy = out + G;
  float* o_value = out + 2 * G;
  float* o_pa = out + 3 * G;
  float* o_pna = out + 3 * G + GA;

  char* w = (char*)d_ws;
  size_t off = 0;
  u16* qna = (u16*)(w + off); off += (size_t)N * 64 * 2;
  float* Su = (float*)(w + off); off += (size_t)GA * 4;
  float* zero_base = (float*)(w + off);
  float* q_a = (float*)(w + off); off += (size_t)GA * 4;
  float* pa_un = (float*)(w + off); off += (size_t)GA * 4;
  float* Sn_at = (float*)(w + off); off += (size_t)G * 4;
  int nzero = 2 * GA + G;
  int* seg_start = (int*)(w + off); off += (size_t)(G + 1) * 4;
  int* mkind = (int*)(w + off); off += 256;
  off = (off + 255) & ~(size_t)255;
  u16* Wpack = (u16*)(w + off); off += (size_t)320 * 256 * 2;
  u16* nga_bf = (u16*)(w + off);
  size_t need_bf = off + (size_t)N * 64 * 2;
  int nga_is_bf = (ws_size >= need_bf) ? 1 : 0;
  float* nga_f32 = o_pna;   // fallback: f32 logits staged in d_out, sweep in-place

  int zero_blocks = (nzero + 255) / 256;
  k0_fused<<<2 + 80 + zero_blocks, 256, 0, stream>>>(
      n_nodes, (const unsigned int*)action_mask, w_node, W_agn, W_nga, W_qna, W_qan,
      seg_start, mkind, zero_base, nzero, Wpack, G, GA / 4);
  k1_gemm<<<N / (TILES * 64), 256, 0, stream>>>(
      values, Wpack, indices, action_mask, mkind,
      b_agn, b_nga, b_qna, b_qan,
      nga_bf, nga_f32, qna, q_a, pa_un, Sn_at, nga_is_bf);
  k2_segment<<<G, 1024, 0, stream>>>(nga_bf, nga_f32, qna, seg_start,
                                     action_mask, mkind, q_a, pa_un, Sn_at,
                                     o_pa, o_entropy, o_value, Su, o_pna, nga_is_bf);
  k3_logprob<<<(G + 255) / 256, 256, 0, stream>>>(
      o_pa, nga_bf, nga_f32, indices, a_action, a_node,
      action_mask, mkind, n_nodes, Su, o_logprob, G, nga_is_bf);
}